// Round 13
// baseline (144.066 us; speedup 1.0000x reference)
//
#include <hip/hip_runtime.h>
#include <hip/hip_bf16.h>
#include <stdint.h>

typedef unsigned long long u64;

#define AN 15
#define HH 200
#define WW 320
#define HWSZ (HH*WW)          // 64000
#define PER (AN*HWSZ)         // 960000 anchors per image
#define NB 8
#define K_PRE 2000
#define K_POST 1000
#define SORTN 4096            // sort size / candidate cap
#define HBINS 4096
#define HBLK 64               // k_hc blocks per image
#define FSLICE 512            // floor-buffer slots per block (mean 344, +9 sigma)
#define NMS_TH 0.7f
#define BBOX_CLIP_F 4.135166556742356f   // log(1000/16)
#define FLOOR12 3072u         // key12 of value 2.0f; P(x>=2.0)~2.3% for N(0,1)

// padded LDS index for the sort: lane stride 72B -> <=4-way bank conflicts
#define PHI(x) ((x) + ((x) >> 3))

__device__ __forceinline__ unsigned keyOfU(unsigned u) {
    return (u & 0x80000000u) ? ~u : (u | 0x80000000u);
}
__device__ __forceinline__ float valOf(unsigned k) {
    unsigned u = (k & 0x80000000u) ? (k ^ 0x80000000u) : ~k;
    return __uint_as_float(u);
}

// ---------- 1: stream cls -> floor-buffer slices + per-block counts ---------
// cnts written by plain store every run (no init kernel, no global atomics)
__global__ __launch_bounds__(256)
void k_hc(const uint4* __restrict__ cls4, u64* __restrict__ fbuf,
          unsigned* __restrict__ cnts) {
    int n = blockIdx.y;
    __shared__ unsigned cnt;
    if (threadIdx.x == 0) cnt = 0;
    __syncthreads();
    u64* slice = fbuf + ((size_t)n * HBLK + blockIdx.x) * FSLICE;
    const uint4* p = cls4 + (size_t)n * (PER / 4);
    int stride = gridDim.x * 256;

#define PROC(vv, ii) {                                                        \
        unsigned kk[4] = {keyOfU((vv).x), keyOfU((vv).y), keyOfU((vv).z),     \
                          keyOfU((vv).w)};                                    \
        int i0 = (ii) * 4;                                                    \
        int a = i0 / HWSZ;                                                    \
        int r0 = i0 - a * HWSZ;                                               \
        _Pragma("unroll")                                                     \
        for (int c = 0; c < 4; ++c) {                                         \
            if ((kk[c] >> 20) >= FLOOR12) {                                   \
                unsigned pos = atomicAdd(&cnt, 1u);                           \
                if (pos < FSLICE) {                                           \
                    unsigned idx = (unsigned)((r0 + c) * AN + a);             \
                    slice[pos] = ((u64)kk[c] << 32) | (u64)(~idx);            \
                }                                                             \
            }                                                                 \
        }                                                                     \
    }

    int i = blockIdx.x * 256 + threadIdx.x;
    for (; i + stride < PER / 4; i += 2 * stride) {
        uint4 a4 = p[i];
        uint4 b4 = p[i + stride];
        PROC(a4, i) PROC(b4, i + stride)
    }
    if (i < PER / 4) { uint4 a4 = p[i]; PROC(a4, i) }
#undef PROC

    __syncthreads();
    unsigned c0 = cnt;
    if (threadIdx.x == 0) cnts[n * HBLK + blockIdx.x] = c0;   // raw count
    unsigned cz = (c0 > FSLICE) ? FSLICE : c0;
    for (unsigned t = cz + threadIdx.x; t < FSLICE; t += 256) slice[t] = 0ull;
}

// ---------- 2: per-image mega-kernel: select + filter + sort + decode -------
__global__ __launch_bounds__(512)
void k_mid(const uint4* __restrict__ cls4, const u64* __restrict__ fbuf,
           const unsigned* __restrict__ cnts, const float* __restrict__ reg,
           const float* __restrict__ anchors, const int* __restrict__ pih,
           const int* __restrict__ piw,
           float* __restrict__ boxes_s, float* __restrict__ scores_s) {
    int n = blockIdx.x;
    int tid = threadIdx.x;
    __shared__ unsigned lh[HBINS];             // 16 KB
    __shared__ unsigned L[512];                // 2 KB scan buffer
    __shared__ u64 sb[PHI(SORTN - 1) + 1];     // 36.9 KB sort buffer
    __shared__ unsigned sT12, sMode, fcnt;

    // --- A: total count + overflow detection (mode select) ---
    if (tid < HBLK) L[tid] = cnts[n * HBLK + tid];
    __syncthreads();
    if (tid == 0) {
        unsigned tot = 0; unsigned ovf = 0;
        for (int b = 0; b < HBLK; ++b) { tot += L[b]; ovf |= (L[b] > FSLICE); }
        sMode = (tot >= K_PRE && !ovf) ? 0u : 1u;
    }
    __syncthreads();
    unsigned mode = sMode;

    // --- B: 12-bit histogram (fbuf entries in mode 0; full cls in mode 1) ---
    for (int b = tid; b < HBINS; b += 512) lh[b] = 0;
    __syncthreads();
    if (mode == 0) {
        const u64* src = fbuf + (size_t)n * HBLK * FSLICE;
        for (int t = tid; t < HBLK * FSLICE; t += 512) {
            unsigned k12 = (unsigned)(src[t] >> 52);
            if (k12 >= FLOOR12) atomicAdd(&lh[k12], 1u);   // zero-pads skipped
        }
    } else {
        const uint4* p = cls4 + (size_t)n * (PER / 4);
        for (int i = tid; i < PER / 4; i += 512) {
            uint4 v = p[i];
            atomicAdd(&lh[keyOfU(v.x) >> 20], 1u);
            atomicAdd(&lh[keyOfU(v.y) >> 20], 1u);
            atomicAdd(&lh[keyOfU(v.z) >> 20], 1u);
            atomicAdd(&lh[keyOfU(v.w) >> 20], 1u);
        }
    }
    __syncthreads();

    // --- C: suffix-scan 4096 bins (8 bins/thread) -> T12 (crossing exists) ---
    unsigned s[8];
    {
        uint4 v0 = *(const uint4*)(lh + 8 * tid);
        uint4 v1 = *(const uint4*)(lh + 8 * tid + 4);
        s[7] = v1.w; s[6] = v1.z + s[7]; s[5] = v1.y + s[6]; s[4] = v1.x + s[5];
        s[3] = v0.w + s[4]; s[2] = v0.z + s[3]; s[1] = v0.y + s[2]; s[0] = v0.x + s[1];
    }
    __syncthreads();
    L[tid] = s[0];
    __syncthreads();
    for (int off = 1; off < 512; off <<= 1) {
        unsigned x = L[tid] + ((tid + off < 512) ? L[tid + off] : 0u);
        __syncthreads(); L[tid] = x; __syncthreads();
    }
    unsigned tail = (tid < 511) ? L[tid + 1] : 0u;
#pragma unroll
    for (int e = 0; e < 8; ++e) {
        unsigned sfE = s[e] + tail;
        unsigned sfN = (e < 7) ? (s[e + 1] + tail) : tail;
        if (sfE >= K_PRE && sfN < K_PRE) sT12 = 8u * tid + e;   // unique winner
    }
    __syncthreads();
    unsigned T12 = sT12;

    // --- D: filter -> sb (LDS), zero-pad to SORTN ---
    if (tid == 0) fcnt = 0;
    __syncthreads();
    if (mode == 0) {
        const u64* src = fbuf + (size_t)n * HBLK * FSLICE;
        for (int t = tid; t < HBLK * FSLICE; t += 512) {
            u64 e = src[t];
            if ((unsigned)(e >> 52) >= T12) {
                unsigned pos = atomicAdd(&fcnt, 1u);
                if (pos < SORTN) sb[PHI((int)pos)] = e;
            }
        }
    } else {
        const uint4* p = cls4 + (size_t)n * (PER / 4);
        for (int i = tid; i < PER / 4; i += 512) {
            uint4 v = p[i];
            unsigned kk[4] = {keyOfU(v.x), keyOfU(v.y), keyOfU(v.z), keyOfU(v.w)};
            int i0 = i * 4;
            int a = i0 / HWSZ;
            int r0 = i0 - a * HWSZ;
#pragma unroll
            for (int c = 0; c < 4; ++c) {
                if ((kk[c] >> 20) >= T12) {
                    unsigned pos = atomicAdd(&fcnt, 1u);
                    if (pos < SORTN) {
                        unsigned idx = (unsigned)((r0 + c) * AN + a);
                        sb[PHI((int)pos)] = ((u64)kk[c] << 32) | (u64)(~idx);
                    }
                }
            }
        }
    }
    __syncthreads();
    unsigned fc = fcnt; if (fc > SORTN) fc = SORTN;
    for (unsigned t = fc + tid; t < SORTN; t += 512) sb[PHI((int)t)] = 0ull;
    __syncthreads();

    // --- E: register-hybrid bitonic sort of 4096 in sb ---
    u64 r[8];
#define CE(a_, b_, d_) { bool sw_ = (d_) ? (r[a_] < r[b_]) : (r[a_] > r[b_]); \
                         if (sw_) { u64 t_ = r[a_]; r[a_] = r[b_]; r[b_] = t_; } }
    {   // k=2 and k=4 levels fully in registers on own 8 elements
#pragma unroll
        for (int e = 0; e < 8; ++e) r[e] = sb[9 * tid + e];   // PHI(8t+e)=9t+e
        CE(0, 1, true)  CE(2, 3, false) CE(4, 5, true)  CE(6, 7, false)
        CE(0, 2, true)  CE(1, 3, true)  CE(4, 6, false) CE(5, 7, false)
        CE(0, 1, true)  CE(2, 3, true)  CE(4, 5, false) CE(6, 7, false)
#pragma unroll
        for (int e = 0; e < 8; ++e) sb[9 * tid + e] = r[e];
        __syncthreads();
    }
    for (int k = 8; k <= SORTN; k <<= 1) {
        for (int j = k >> 1; j >= 8; j >>= 1) {
#pragma unroll
            for (int ss = 0; ss < 4; ++ss) {
                int c = tid + ss * 512;
                int i = ((c & ~(j - 1)) << 1) | (c & (j - 1));
                int p = i | j;
                bool dir = (i & k) == 0;
                u64 a = sb[PHI(i)], b = sb[PHI(p)];
                bool sw = dir ? (a < b) : (a > b);
                if (sw) { sb[PHI(i)] = b; sb[PHI(p)] = a; }
            }
            __syncthreads();
        }
        {   // register pass: j = 4, 2, 1 (dir uniform per thread for k>=8)
            bool d = ((8 * tid) & k) == 0;
#pragma unroll
            for (int e = 0; e < 8; ++e) r[e] = sb[9 * tid + e];
            CE(0, 4, d) CE(1, 5, d) CE(2, 6, d) CE(3, 7, d)
            CE(0, 2, d) CE(1, 3, d) CE(4, 6, d) CE(5, 7, d)
            CE(0, 1, d) CE(2, 3, d) CE(4, 5, d) CE(6, 7, d)
#pragma unroll
            for (int e = 0; e < 8; ++e) sb[9 * tid + e] = r[e];
            __syncthreads();
        }
    }
#undef CE

    // --- F: decode top-2000 + stable valid-first partition (512 thr, q<4) ---
    float fh = (float)(*pih);
    float fw = (float)(*piw);

    float bx[4][4]; float sc[4]; int pred[4];
#pragma unroll
    for (int q = 0; q < 4; ++q) {
        int t = tid + 512 * q;
        pred[q] = 0; sc[q] = -1.0f;
        bx[q][0] = bx[q][1] = bx[q][2] = bx[q][3] = 0.f;
        if (t < K_PRE) {
            u64 e = sb[PHI(t)];
            unsigned key = (unsigned)(e >> 32);
            unsigned idx = ~((unsigned)e);
            float v = valOf(key);
            float sgm = 1.0f / (1.0f + expf(-v));
            int a = (int)(idx % AN);
            int rr = (int)(idx / AN);
            size_t base = ((size_t)(n * AN + a) * 4) * HWSZ + rr;
            float dx = reg[base];
            float dy = reg[base + HWSZ];
            float dw = reg[base + 2 * (size_t)HWSZ];
            float dh = reg[base + 3 * (size_t)HWSZ];
            float4 an4 = ((const float4*)anchors)[idx];
            float wa = an4.z - an4.x, ha = an4.w - an4.y;
            float cxa = an4.x + 0.5f * wa, cya = an4.y + 0.5f * ha;
            dw = fminf(dw, BBOX_CLIP_F); dh = fminf(dh, BBOX_CLIP_F);
            float cx = dx * wa + cxa, cy = dy * ha + cya;
            float w = wa * expf(dw), h = ha * expf(dh);
            float x1 = cx - 0.5f * w, y1 = cy - 0.5f * h;
            float x2 = cx + 0.5f * w, y2 = cy + 0.5f * h;
            x1 = fminf(fmaxf(x1, 0.f), fw);
            y1 = fminf(fmaxf(y1, 0.f), fh);
            x2 = fminf(fmaxf(x2, 0.f), fw);
            y2 = fminf(fmaxf(y2, 0.f), fh);
            bool valid = ((x2 - x1) >= 1.0f) && ((y2 - y1) >= 1.0f);
            bx[q][0] = x1; bx[q][1] = y1; bx[q][2] = x2; bx[q][3] = y2;
            sc[q] = sgm; pred[q] = valid ? 1 : 0;
        }
    }
    __syncthreads();

    __shared__ u64 ww[32];
    __shared__ int wpfx[33];
    int lane = tid & 63, wid = tid >> 6;     // 8 waves
#pragma unroll
    for (int q = 0; q < 4; ++q) {
        u64 bal = __ballot(pred[q] != 0);
        if (lane == 0) ww[wid + 8 * q] = bal;
    }
    __syncthreads();
    if (tid == 0) {
        int acc = 0;
#pragma unroll
        for (int w2 = 0; w2 < 32; ++w2) { wpfx[w2] = acc; acc += (int)__popcll(ww[w2]); }
        wpfx[32] = acc;
    }
    __syncthreads();
    int V = wpfx[32];

#pragma unroll
    for (int q = 0; q < 4; ++q) {
        int t = tid + 512 * q;
        if (t < K_PRE) {
            int wi = t >> 6;
            int before = wpfx[wi] + (int)__popcll(ww[wi] & ((1ull << (unsigned)lane) - 1ull));
            int pos = pred[q] ? before : (V + (t - before));
            float4 b4; b4.x = bx[q][0]; b4.y = bx[q][1]; b4.z = bx[q][2]; b4.w = bx[q][3];
            ((float4*)boxes_s)[(size_t)n * K_PRE + pos] = b4;
            scores_s[(size_t)n * K_PRE + pos] = pred[q] ? sc[q] : -1.0f;
        }
    }
}

// ---------- 3: transposed IoU mask, triangular (rb,cb) tile per block -------
__global__ __launch_bounds__(64)
void k_maskT(const float* __restrict__ boxes_s, u64* __restrict__ maskT) {
    int n = blockIdx.y;
    int p = blockIdx.x;                      // 0..527 triangular pair index
    int lane = threadIdx.x;
    int cb = (int)((sqrtf(8.0f * (float)p + 1.0f) - 1.0f) * 0.5f);
    while ((cb + 1) * (cb + 2) / 2 <= p) ++cb;
    while (cb * (cb + 1) / 2 > p) --cb;
    int rb = p - cb * (cb + 1) / 2;          // 0 <= rb <= cb < 32

    __shared__ float rx1[64], ry1[64], rx2[64], ry2[64], rar[64];
    int c = cb * 64 + lane;
    bool cok = c < K_PRE;
    float4 c4; c4.x = c4.y = c4.z = c4.w = 0.f;
    if (cok) c4 = ((const float4*)boxes_s)[(size_t)n * K_PRE + c];
    float areaC = (c4.z - c4.x) * (c4.w - c4.y);

    int r = rb * 64 + lane;
    float4 r4; r4.x = r4.y = r4.z = r4.w = 0.f;
    if (r < K_PRE) r4 = ((const float4*)boxes_s)[(size_t)n * K_PRE + r];
    rx1[lane] = r4.x; ry1[lane] = r4.y; rx2[lane] = r4.z; ry2[lane] = r4.w;
    rar[lane] = (r4.z - r4.x) * (r4.w - r4.y);
    __syncthreads();

    u64 bits = 0;
    int bmax = 0;
    if (cok) { bmax = c - rb * 64; if (bmax > 64) bmax = 64; }
    for (int b = 0; b < bmax; ++b) {
        float ix = fminf(c4.z, rx2[b]) - fmaxf(c4.x, rx1[b]); ix = fmaxf(ix, 0.f);
        float iy = fminf(c4.w, ry2[b]) - fmaxf(c4.y, ry1[b]); iy = fmaxf(iy, 0.f);
        float inter = ix * iy;
        float iou = inter / (rar[b] + areaC - inter);
        if (iou > NMS_TH) bits |= (1ull << b);
    }
    maskT[((size_t)n * 32 + rb) * 2048 + c] = bits;
}

// ---------- 4: greedy NMS ballot-fixpoint + output (tail zeroed) ------------
__global__ __launch_bounds__(64)
void k_scanT(const u64* __restrict__ maskT, const float* __restrict__ boxes_s,
             const float* __restrict__ scores_s, float* __restrict__ out) {
    int n = blockIdx.x;
    int lane = threadIdx.x;       // 64 threads, single wave
    __shared__ float ls[2048];
    __shared__ u64 keptw[32];
    for (int i = lane; i < 500; i += 64)
        ((float4*)ls)[i] = ((const float4*)(scores_s + (size_t)n * K_PRE))[i];
    if (lane < 48) ls[2000 + lane] = -1.0f;
    if (lane < 32) keptw[lane] = 0ull;
    __syncthreads();

    const u64* mb = maskT + (size_t)n * 32 * 2048;
    int kept_total = 0;

    u64 wv[32];
#pragma unroll
    for (int rb = 0; rb < 32; ++rb) wv[rb] = mb[(size_t)rb * 2048 + lane];

    for (int f = 0; f < 32; ++f) {
        int c = f * 64 + lane;

        u64 wn[32];
        if (f < 31) {
            int cn = c + 64;
#pragma unroll
            for (int rb = 0; rb < 32; ++rb) wn[rb] = mb[(size_t)rb * 2048 + cn];
        }

        // rb > f words may be unwritten garbage, but keptw[rb>=f] == 0
        u64 hit = 0;
#pragma unroll
        for (int rb = 0; rb < 32; ++rb) hit |= (wv[rb] & keptw[rb]);
        bool ext = hit != 0ull;
        u64 diag = wv[f];

        bool v = (ls[c] >= 0.0f) && !ext;
        u64 kept = __ballot(v);
        while (true) {
            u64 nk = __ballot(v && ((diag & kept) == 0ull));
            if (nk == kept) break;
            kept = nk;
        }

        if ((kept >> lane) & 1ull) {
            int rank = kept_total + (int)__popcll(kept & ((1ull << lane) - 1ull));
            if (rank < K_POST) {
                float4 b4 = ((const float4*)boxes_s)[(size_t)n * K_PRE + c];
                ((float4*)out)[(size_t)n * K_POST + rank] = b4;
                out[(size_t)NB * K_POST * 4 + (size_t)n * K_POST + rank] = ls[c];
            }
        }
        kept_total += (int)__popcll(kept);
        if (lane == 0) keptw[f] = kept;
        if (kept_total >= K_POST || f == 31) break;
#pragma unroll
        for (int rb = 0; rb < 32; ++rb) wv[rb] = wn[rb];
    }

    // zero output tail (every output byte written each replay)
    int start = (kept_total < K_POST) ? kept_total : K_POST;
    float4 z4; z4.x = z4.y = z4.z = z4.w = 0.f;
    for (int rk = start + lane; rk < K_POST; rk += 64) {
        ((float4*)out)[(size_t)n * K_POST + rk] = z4;
        out[(size_t)NB * K_POST * 4 + (size_t)n * K_POST + rk] = 0.f;
    }
}

extern "C" void kernel_launch(void* const* d_in, const int* in_sizes, int n_in,
                              void* d_out, int out_size, void* d_ws, size_t ws_size,
                              hipStream_t stream) {
    const float* cls     = (const float*)d_in[0];
    const float* regr    = (const float*)d_in[1];
    const float* anchors = (const float*)d_in[2];
    const int*   pih     = (const int*)d_in[3];
    const int*   piw     = (const int*)d_in[4];
    float* out = (float*)d_out;

    char* w = (char*)d_ws;
    u64*      maskT   = (u64*)(w + 0);                 // 8*32*2048*8 = 4,194,304
    u64*      fbuf    = (u64*)(w + 4194304);           // 8*64*512*8  = 2,097,152
    unsigned* cnts    = (unsigned*)(w + 6291456);      // 8*64*4      =     2,048
    float*    boxes_s = (float*)(w + 6293504);         // 8*2000*16   =   256,000
    float*    scores_s= (float*)(w + 6549504);         // 8*2000*4    =    64,000
    // end 6,613,504 bytes

    k_hc<<<dim3(HBLK, NB), 256, 0, stream>>>((const uint4*)cls, fbuf, cnts);
    k_mid<<<NB, 512, 0, stream>>>((const uint4*)cls, fbuf, cnts, regr, anchors,
                                  pih, piw, boxes_s, scores_s);
    k_maskT<<<dim3(528, NB), 64, 0, stream>>>(boxes_s, maskT);
    k_scanT<<<NB, 64, 0, stream>>>(maskT, boxes_s, scores_s, out);
    (void)in_sizes; (void)n_in; (void)ws_size; (void)out_size;
}